// Round 4
// baseline (703.151 us; speedup 1.0000x reference)
//
#include <hip/hip_runtime.h>
#include <hip/hip_bf16.h>
#include <math.h>

// ---------------------------------------------------------------------------
// TransformerBlock on MI355X. B=4, C=2048, D=1024, H=16, dh=64, HIDDEN=4096.
// All matmuls in bf16 MFMA (16x16x32), fp32 accum. LN/softmax fp32.
// Round 4: attention VALU diet (scale folded into Q, mask only on diagonal
// tiles, row-sum via MFMA ones-column, intrinsic bf16 converts) + LPT
// dispatch (heavy q-tiles first) at 4 blocks/CU.
// ---------------------------------------------------------------------------

typedef __attribute__((ext_vector_type(8))) short short8;   // 8 x bf16 fragment
typedef __attribute__((ext_vector_type(4))) float f32x4;

typedef const __attribute__((address_space(1))) unsigned int glb_u32;
typedef __attribute__((address_space(3))) unsigned int lds_u32;

__device__ __forceinline__ void gload16(const void* g, void* l) {
  // 16B per lane, wave-uniform LDS base; HW writes base + lane*16.
  __builtin_amdgcn_global_load_lds((glb_u32*)g, (lds_u32*)l, 16, 0, 0);
}

__device__ __forceinline__ unsigned short f2bf(float f) {
  union { __hip_bfloat16 h; unsigned short u; } c;
  c.h = __float2bfloat16(f);        // compiler emits v_cvt_pk_bf16_f32 pairs
  return c.u;
}

__device__ __forceinline__ float bf2f(unsigned short u) {
  union { unsigned int u; float f; } c;
  c.u = ((unsigned int)u) << 16;
  return c.f;
}

__device__ __forceinline__ float gelu_exact(float v) {
  return 0.5f * v * (1.0f + erff(v * 0.7071067811865475f));
}

// ---------------------------------------------------------------------------
// Weight transpose + fp32->bf16 convert:  in (K x N) fp32  ->  out (N x K) bf16
// ---------------------------------------------------------------------------
__global__ __launch_bounds__(256) void transpose_convert(
    const float* __restrict__ in, unsigned short* __restrict__ outp, int K, int N) {
  __shared__ float tile[32][33];
  const int bk = blockIdx.x * 32, bn = blockIdx.y * 32;
  const int t = threadIdx.x;
  const int r = t >> 5, c = t & 31;
#pragma unroll
  for (int p = 0; p < 4; ++p)
    tile[r + p * 8][c] = in[(size_t)(bk + r + p * 8) * N + bn + c];
  __syncthreads();
#pragma unroll
  for (int p = 0; p < 4; ++p)
    outp[(size_t)(bn + r + p * 8) * K + bk + c] = f2bf(tile[c][r + p * 8]);
}

// ---------------------------------------------------------------------------
// V transpose: qkv V-part (b,q,h,d) -> vT[bh][d][q]  (bf16, per-(b,h) 64x2048)
// ---------------------------------------------------------------------------
__global__ __launch_bounds__(256) void transpose_v(
    const unsigned short* __restrict__ qkv, unsigned short* __restrict__ vT) {
  __shared__ unsigned short tile[64][68];   // pad to de-pattern banks
  const int bh = blockIdx.y;                // 0..63
  const int b = bh >> 4, h = bh & 15;
  const int q0 = blockIdx.x * 64;
  const int t = threadIdx.x;
  const int r = t >> 3, c8 = t & 7;         // r: 0..31
#pragma unroll
  for (int p = 0; p < 2; ++p) {
    const int q = r + p * 32;
    short8 v = *(const short8*)(qkv + (size_t)(b * 2048 + q0 + q) * 3072 + 2048 + h * 64 + c8 * 8);
    *(short8*)(&tile[q][c8 * 8]) = v;
  }
  __syncthreads();
#pragma unroll
  for (int p = 0; p < 2; ++p) {
    const int d = r + p * 32;
    short8 v;
#pragma unroll
    for (int j = 0; j < 8; ++j) v[j] = tile[c8 * 8 + j][d];
    *(short8*)(vT + ((size_t)bh * 64 + d) * 2048 + q0 + c8 * 8) = v;
  }
}

// ---------------------------------------------------------------------------
// LayerNorm: x (rows x 1024) fp32 -> out bf16.  One 256-thread block per row.
// ---------------------------------------------------------------------------
__global__ __launch_bounds__(256) void layernorm_k(
    const float* __restrict__ x, const float* __restrict__ gamma,
    const float* __restrict__ beta, unsigned short* __restrict__ out) {
  const int row = blockIdx.x;
  const int t = threadIdx.x;
  const float4 v = ((const float4*)(x + (size_t)row * 1024))[t];
  float s = v.x + v.y + v.z + v.w;
  float sq = v.x * v.x + v.y * v.y + v.z * v.z + v.w * v.w;
#pragma unroll
  for (int sh = 32; sh >= 1; sh >>= 1) {
    s += __shfl_xor(s, sh);
    sq += __shfl_xor(sq, sh);
  }
  __shared__ float ps[4], pq[4];
  if ((t & 63) == 0) { ps[t >> 6] = s; pq[t >> 6] = sq; }
  __syncthreads();
  s = ps[0] + ps[1] + ps[2] + ps[3];
  sq = pq[0] + pq[1] + pq[2] + pq[3];
  const float mean = s * (1.0f / 1024.0f);
  const float var = sq * (1.0f / 1024.0f) - mean * mean;
  const float rstd = rsqrtf(var + 1e-5f);
  const float4 g = ((const float4*)gamma)[t];
  const float4 be = ((const float4*)beta)[t];
  ushort4 ov;
  ov.x = f2bf(g.x * (v.x - mean) * rstd + be.x);
  ov.y = f2bf(g.y * (v.y - mean) * rstd + be.y);
  ov.z = f2bf(g.z * (v.z - mean) * rstd + be.z);
  ov.w = f2bf(g.w * (v.w - mean) * rstd + be.w);
  ((ushort4*)(out + (size_t)row * 1024))[t] = ov;
}

// ---------------------------------------------------------------------------
// GEMM  C(MxN) = A(MxK,bf16) * Bt(NxK,bf16)^T  + bias [+gelu] [+f32 residual]
// 128x128 tile, BK=64, 4 waves (2x2), per-wave 64x64 = 4x4 frags of 16x16x32.
// Staging: global_load_lds width=16, linear LDS dest, PRE-SWIZZLED global
// source (rule #21): LDS[r][c8] = global[r][c8 ^ (r&7)]; reads XOR again.
// XCD-aware block swizzle (nwg % 8 == 0 for all launches here).
// EPI: 0 = bf16 out (bias), 1 = bf16 out (bias+gelu), 2 = f32 out (bias+res)
// ---------------------------------------------------------------------------
template <int EPI>
__global__ __launch_bounds__(256) void gemm_bt(
    const unsigned short* __restrict__ A, const unsigned short* __restrict__ Bt,
    const float* __restrict__ bias, const float* __restrict__ res,
    void* __restrict__ outp, int M, int N, int K) {
  __shared__ unsigned short lA[128 * 64];
  __shared__ unsigned short lB[128 * 64];
  const int t = threadIdx.x;
  const int lane = t & 63;
  const int wave = t >> 6;
  const int l15 = lane & 15, l4 = lane >> 4;

  // XCD swizzle: consecutive dispatch ids round-robin XCDs; give each XCD a
  // contiguous chunk of the work space so L2 panels are shared within an XCD.
  const int gx = gridDim.x;
  int lin = blockIdx.y * gx + blockIdx.x;
  const int cpx = (gx * gridDim.y) >> 3;
  lin = (lin & 7) * cpx + (lin >> 3);
  const int m0 = (lin / gx) * 128, n0 = (lin % gx) * 128;
  const int wm = (wave >> 1) * 64, wn = (wave & 1) * 64;

  f32x4 acc[4][4];
#pragma unroll
  for (int a_ = 0; a_ < 4; ++a_)
#pragma unroll
    for (int b_ = 0; b_ < 4; ++b_) acc[a_][b_] = f32x4{0.f, 0.f, 0.f, 0.f};

  // staging geometry (per wave: 4 chunks of A + 4 of B; chunk = 1KB = 8 rows)
  const int s_sub = lane >> 3;               // 0..7 row-in-chunk
  const int s_c8 = lane & 7;                 // 16B column chunk

  for (int k0 = 0; k0 < K; k0 += 64) {
    __syncthreads();                         // prior iter's LDS reads done
#pragma unroll
    for (int j = 0; j < 4; ++j) {
      const int chunk = wave * 4 + j;        // 0..15
      const int r = chunk * 8 + s_sub;       // 0..127
      const int c8s = s_c8 ^ (r & 7);        // pre-swizzled source column
      gload16(A + (size_t)(m0 + r) * K + k0 + c8s * 8, lA + chunk * 512);
      gload16(Bt + (size_t)(n0 + r) * K + k0 + c8s * 8, lB + chunk * 512);
    }
    __syncthreads();                         // drains vmcnt -> LDS ready
#pragma unroll
    for (int ks = 0; ks < 2; ++ks) {
      short8 af[4], bf[4];
#pragma unroll
      for (int mf = 0; mf < 4; ++mf) {
        const int r = wm + mf * 16 + l15;
        af[mf] = *(const short8*)(lA + r * 64 + (((ks * 4 + l4) ^ (r & 7)) * 8));
      }
#pragma unroll
      for (int nf = 0; nf < 4; ++nf) {
        const int r = wn + nf * 16 + l15;
        bf[nf] = *(const short8*)(lB + r * 64 + (((ks * 4 + l4) ^ (r & 7)) * 8));
      }
#pragma unroll
      for (int mf = 0; mf < 4; ++mf)
#pragma unroll
        for (int nf = 0; nf < 4; ++nf)
          acc[mf][nf] = __builtin_amdgcn_mfma_f32_16x16x32_bf16(
              af[mf], bf[nf], acc[mf][nf], 0, 0, 0);
    }
  }
  // epilogue: D row = (lane>>4)*4 + reg, col = lane&15  (m89-verified layout)
#pragma unroll
  for (int mf = 0; mf < 4; ++mf)
#pragma unroll
    for (int i = 0; i < 4; ++i) {
      const int gm = m0 + wm + mf * 16 + l4 * 4 + i;
#pragma unroll
      for (int nf = 0; nf < 4; ++nf) {
        const int gn = n0 + wn + nf * 16 + l15;
        float v = acc[mf][nf][i] + bias[gn];
        if constexpr (EPI == 1) v = gelu_exact(v);
        if constexpr (EPI == 2) {
          v += res[(size_t)gm * N + gn];
          ((float*)outp)[(size_t)gm * N + gn] = v;
        } else {
          ((unsigned short*)outp)[(size_t)gm * N + gn] = f2bf(v);
        }
      }
    }
}

// ---------------------------------------------------------------------------
// Attention tile: one 32x64 S-tile -> online softmax -> O += P V.
// Q pre-scaled by 1/8; MASK only instantiated for diagonal tiles.
// Row-sum accumulated via MFMA with all-ones B fragment (os).
// ---------------------------------------------------------------------------
template <bool MASK>
__device__ __forceinline__ void attn_tile(
    int kt, int q0, const short8 (&qf)[2][2], f32x4 (&o)[2][4], f32x4 (&os)[2],
    float (&mrow)[2][4],
    const unsigned short* lK, const unsigned short* lV,
    unsigned short* lp, int l15, int l4) {
  // S = Q K^T  (Q pre-scaled)
  f32x4 s[2][4];
#pragma unroll
  for (int mf = 0; mf < 2; ++mf)
#pragma unroll
    for (int nf = 0; nf < 4; ++nf) s[mf][nf] = f32x4{0.f, 0.f, 0.f, 0.f};
#pragma unroll
  for (int ks = 0; ks < 2; ++ks) {
    short8 kf[4];
#pragma unroll
    for (int nf = 0; nf < 4; ++nf) {
      const int r = nf * 16 + l15;
      kf[nf] = *(const short8*)(lK + r * 64 + (((ks * 4 + l4) ^ (r & 7)) * 8));
    }
#pragma unroll
    for (int mf = 0; mf < 2; ++mf)
#pragma unroll
      for (int nf = 0; nf < 4; ++nf)
        s[mf][nf] = __builtin_amdgcn_mfma_f32_16x16x32_bf16(
            qf[mf][ks], kf[nf], s[mf][nf], 0, 0, 0);
  }
  if constexpr (MASK) {
#pragma unroll
    for (int mf = 0; mf < 2; ++mf)
#pragma unroll
      for (int i = 0; i < 4; ++i) {
        const int gq = q0 + mf * 16 + l4 * 4 + i;
#pragma unroll
        for (int nf = 0; nf < 4; ++nf) {
          const int gk = kt * 64 + nf * 16 + l15;
          s[mf][nf][i] = (gk <= gq) ? s[mf][nf][i] : -1e30f;
        }
      }
  }
  // online softmax: row max via 16-lane shuffle reduce; sum via MFMA below
  float alpha[2][4];
#pragma unroll
  for (int mf = 0; mf < 2; ++mf)
#pragma unroll
    for (int i = 0; i < 4; ++i) {
      float mx = fmaxf(fmaxf(s[mf][0][i], s[mf][1][i]),
                       fmaxf(s[mf][2][i], s[mf][3][i]));
#pragma unroll
      for (int sh = 1; sh < 16; sh <<= 1) mx = fmaxf(mx, __shfl_xor(mx, sh));
      const float mnew = fmaxf(mrow[mf][i], mx);
      alpha[mf][i] = __expf(mrow[mf][i] - mnew);
      mrow[mf][i] = mnew;
#pragma unroll
      for (int nf = 0; nf < 4; ++nf)
        s[mf][nf][i] = __expf(s[mf][nf][i] - mnew);
    }
  // rescale O and row-sum accumulator
#pragma unroll
  for (int mf = 0; mf < 2; ++mf) {
#pragma unroll
    for (int nf = 0; nf < 4; ++nf)
#pragma unroll
      for (int i = 0; i < 4; ++i) o[mf][nf][i] *= alpha[mf][i];
#pragma unroll
    for (int i = 0; i < 4; ++i) os[mf][i] *= alpha[mf][i];
  }
  // P -> bf16 -> per-wave LDS (D-layout scatter, swizzled)
#pragma unroll
  for (int mf = 0; mf < 2; ++mf)
#pragma unroll
    for (int nf = 0; nf < 4; ++nf)
#pragma unroll
      for (int i = 0; i < 4; ++i) {
        const int qr = mf * 16 + l4 * 4 + i;
        const int kb = (nf * 16 + l15) * 2;
        const int byt = qr * 128 + (kb ^ ((qr & 7) << 4));
        lp[byt >> 1] = f2bf(s[mf][nf][i]);
      }
  // O += P V ; os += P * ones
  const short8 ones = {16256, 16256, 16256, 16256, 16256, 16256, 16256, 16256};
#pragma unroll
  for (int ks = 0; ks < 2; ++ks) {
    short8 pf[2], vf[4];
#pragma unroll
    for (int mf = 0; mf < 2; ++mf) {
      const int r = mf * 16 + l15;
      pf[mf] = *(const short8*)(lp + r * 64 + (((ks * 4 + l4) ^ (r & 7)) * 8));
    }
#pragma unroll
    for (int nf = 0; nf < 4; ++nf) {
      const int r = nf * 16 + l15;   // d index
      vf[nf] = *(const short8*)(lV + r * 64 + (((ks * 4 + l4) ^ (r & 7)) * 8));
    }
#pragma unroll
    for (int mf = 0; mf < 2; ++mf) {
      os[mf] = __builtin_amdgcn_mfma_f32_16x16x32_bf16(pf[mf], ones, os[mf], 0, 0, 0);
#pragma unroll
      for (int nf = 0; nf < 4; ++nf)
        o[mf][nf] = __builtin_amdgcn_mfma_f32_16x16x32_bf16(
            pf[mf], vf[nf], o[mf][nf], 0, 0, 0);
    }
  }
}

// ---------------------------------------------------------------------------
// Causal flash attention. qkv: (8192 x 3072) bf16, vT: [bh][64][2048] bf16.
// Grid (64, 16): x = bh (=> bh%8 -> fixed XCD, K/V L2 locality),
// y: qb = 15 - y => heaviest blocks dispatched first (LPT backfill).
// Block = one q-tile (128 rows), 4 waves x 32 rows. K/V staged per 64-k tile.
// ---------------------------------------------------------------------------
__global__ __launch_bounds__(256, 4) void attn_kernel(
    const unsigned short* __restrict__ qkv, const unsigned short* __restrict__ vT,
    unsigned short* __restrict__ attno) {
  __shared__ unsigned short lK[64 * 64];      // [krow][d]  swizzled
  __shared__ unsigned short lV[64 * 64];      // [d][krow]  swizzled
  __shared__ unsigned short lP[4][32 * 64];   // per-wave P, swizzled

  const int bh = blockIdx.x;                  // 0..63
  const int qb = 15 - blockIdx.y;             // heavy first
  const int b = bh >> 4, h = bh & 15;
  const int t = threadIdx.x;
  const int wave = t >> 6, lane = t & 63;
  const int l15 = lane & 15, l4 = lane >> 4;

  const unsigned short* qkvb = qkv + (size_t)b * 2048 * 3072;
  const unsigned short* vTb = vT + (size_t)bh * 64 * 2048;
  const int q0 = qb * 128 + wave * 32;

  // Q fragments hoisted + folded 1/8 scale (exact in bf16: x * 2^-3)
  short8 qf[2][2];
#pragma unroll
  for (int mf = 0; mf < 2; ++mf)
#pragma unroll
    for (int ks = 0; ks < 2; ++ks) {
      const int qr = q0 + mf * 16 + l15;
      const int d = ks * 32 + l4 * 8;
      short8 raw = *(const short8*)(qkvb + (size_t)qr * 3072 + h * 64 + d);
#pragma unroll
      for (int j = 0; j < 8; ++j)
        qf[mf][ks][j] = (short)f2bf(bf2f((unsigned short)raw[j]) * 0.125f);
    }

  f32x4 o[2][4], os[2];
  float mrow[2][4];
#pragma unroll
  for (int mf = 0; mf < 2; ++mf) {
    os[mf] = f32x4{0.f, 0.f, 0.f, 0.f};
#pragma unroll
    for (int i = 0; i < 4; ++i) mrow[mf][i] = -1e30f;
#pragma unroll
    for (int nf = 0; nf < 4; ++nf) o[mf][nf] = f32x4{0.f, 0.f, 0.f, 0.f};
  }

  const int s_sub = lane >> 3, s_c8 = lane & 7;
  const int ktiles = qb * 2 + 2;
  for (int kt = 0; kt < ktiles; ++kt) {
    __syncthreads();                           // prior tile reads done
    // stage K [k][d] and V^T [d][k] via global_load_lds (2 chunks each/wave)
#pragma unroll
    for (int j = 0; j < 2; ++j) {
      const int chunk = wave * 2 + j;          // 0..7
      const int r = chunk * 8 + s_sub;         // 0..63
      const int c8s = s_c8 ^ (r & 7);
      gload16(qkvb + (size_t)(kt * 64 + r) * 3072 + 1024 + h * 64 + c8s * 8,
              lK + chunk * 512);
      gload16(vTb + (size_t)r * 2048 + kt * 64 + c8s * 8, lV + chunk * 512);
    }
    __syncthreads();

    if ((kt * 64) <= (q0 + 31)) {
      if ((kt * 64 + 63) <= q0)
        attn_tile<false>(kt, q0, qf, o, os, mrow, lK, lV, lP[wave], l15, l4);
      else
        attn_tile<true>(kt, q0, qf, o, os, mrow, lK, lV, lP[wave], l15, l4);
    }
  }

  // epilogue: O /= rowsum, store bf16 at (b*2048+q, h*64+d)
#pragma unroll
  for (int mf = 0; mf < 2; ++mf)
#pragma unroll
    for (int i = 0; i < 4; ++i) {
      const float inv = 1.0f / os[mf][i];
      const int gq = q0 + mf * 16 + l4 * 4 + i;
#pragma unroll
      for (int nf = 0; nf < 4; ++nf) {
        const int gd = nf * 16 + l15;
        attno[(size_t)(b * 2048 + gq) * 1024 + h * 64 + gd] =
            f2bf(o[mf][nf][i] * inv);
      }
    }
}

// ---------------------------------------------------------------------------
extern "C" void kernel_launch(void* const* d_in, const int* in_sizes, int n_in,
                              void* d_out, int out_size, void* d_ws, size_t ws_size,
                              hipStream_t stream) {
  const float* x    = (const float*)d_in[0];
  const float* g1   = (const float*)d_in[1];
  const float* be1  = (const float*)d_in[2];
  const float* Wqkv = (const float*)d_in[3];
  const float* bqkv = (const float*)d_in[4];
  const float* Wo   = (const float*)d_in[5];
  const float* bo   = (const float*)d_in[6];
  const float* g2   = (const float*)d_in[7];
  const float* be2  = (const float*)d_in[8];
  const float* W1   = (const float*)d_in[9];
  const float* b1   = (const float*)d_in[10];
  const float* W2   = (const float*)d_in[11];
  const float* b2   = (const float*)d_in[12];
  float* out = (float*)d_out;
  char* ws = (char*)d_ws;

  const size_t MB = 1024ull * 1024ull;
  // lifetimes: qkv (0..64MB) dies before gelu-out reuses it; ln1 (64..80MB)
  // dies before attn-out reuses it; vT (80..96MB) dies before x2 (80..112MB)
  // is written (step 5).
  unsigned short* qkv_g    = (unsigned short*)(ws + 0);        // 48MB qkv / 64MB gelu
  unsigned short* ln1_attn = (unsigned short*)(ws + 64 * MB);  // 16MB ln1 / attn-out
  float*          x2       = (float*)(ws + 80 * MB);           // 32MB
  unsigned short* vT       = (unsigned short*)(ws + 80 * MB);  // 16MB (dead by step 5)
  unsigned short* hbuf     = (unsigned short*)(ws + 112 * MB); // 16MB
  unsigned short* wqkv_bt  = (unsigned short*)(ws + 128 * MB); // 6MB  (3072x1024)
  unsigned short* wo_bt    = (unsigned short*)(ws + 134 * MB); // 2MB  (1024x1024)
  unsigned short* w1_bt    = (unsigned short*)(ws + 136 * MB); // 8MB  (4096x1024)
  unsigned short* w2_bt    = (unsigned short*)(ws + 144 * MB); // 8MB  (1024x4096)

  // 1) weight transposes (fp32 -> bf16, N x K layout)
  transpose_convert<<<dim3(1024 / 32, 3072 / 32), 256, 0, stream>>>(Wqkv, wqkv_bt, 1024, 3072);
  transpose_convert<<<dim3(1024 / 32, 1024 / 32), 256, 0, stream>>>(Wo, wo_bt, 1024, 1024);
  transpose_convert<<<dim3(1024 / 32, 4096 / 32), 256, 0, stream>>>(W1, w1_bt, 1024, 4096);
  transpose_convert<<<dim3(4096 / 32, 1024 / 32), 256, 0, stream>>>(W2, w2_bt, 4096, 1024);

  // 2) ln1(x) -> bf16
  layernorm_k<<<8192, 256, 0, stream>>>(x, g1, be1, ln1_attn);

  // 3) qkv = ln1 @ Wqkv + b_qkv   (8192 x 3072)
  gemm_bt<0><<<dim3(3072 / 128, 8192 / 128), 256, 0, stream>>>(
      ln1_attn, wqkv_bt, bqkv, nullptr, qkv_g, 8192, 3072, 1024);

  // 3b) V -> vT[bh][d][q]
  transpose_v<<<dim3(2048 / 64, 64), 256, 0, stream>>>(qkv_g, vT);

  // 4) causal attention -> ln1_attn (reused as attn-out, 8192 x 1024 bf16)
  attn_kernel<<<dim3(64, 16), 256, 0, stream>>>(qkv_g, vT, ln1_attn);

  // 5) x2 = x + attn @ Wo + b_o  (fp32)
  gemm_bt<2><<<dim3(1024 / 128, 8192 / 128), 256, 0, stream>>>(
      ln1_attn, wo_bt, bo, x, x2, 8192, 1024, 1024);

  // 6) ln2(x2) -> bf16
  layernorm_k<<<8192, 256, 0, stream>>>(x2, g2, be2, hbuf);

  // 7) g = gelu(h @ W1 + b1)  (8192 x 4096 bf16), reuses qkv region
  gemm_bt<1><<<dim3(4096 / 128, 8192 / 128), 256, 0, stream>>>(
      hbuf, w1_bt, b1, nullptr, qkv_g, 8192, 4096, 1024);

  // 8) out = x2 + g @ W2 + b2  (fp32)
  gemm_bt<2><<<dim3(1024 / 128, 8192 / 128), 256, 0, stream>>>(
      qkv_g, w2_bt, b2, x2, out, 8192, 1024, 4096);
}

// Round 5
// 524.000 us; speedup vs baseline: 1.3419x; 1.3419x over previous
//
#include <hip/hip_runtime.h>
#include <hip/hip_bf16.h>
#include <math.h>

// ---------------------------------------------------------------------------
// TransformerBlock on MI355X. B=4, C=2048, D=1024, H=16, dh=64, HIDDEN=4096.
// All matmuls in bf16 MFMA (16x16x32), fp32 accum. LN/softmax fp32.
// Round 5: round-4 VALU diet kept; attn launch_bounds back to (256,2) —
// (256,4) squeezed the unified VGPR/AGPR file to 64 arch regs and spilled
// (FETCH 25->250MB). Register residency beats nominal occupancy.
// ---------------------------------------------------------------------------

typedef __attribute__((ext_vector_type(8))) short short8;   // 8 x bf16 fragment
typedef __attribute__((ext_vector_type(4))) float f32x4;

typedef const __attribute__((address_space(1))) unsigned int glb_u32;
typedef __attribute__((address_space(3))) unsigned int lds_u32;

__device__ __forceinline__ void gload16(const void* g, void* l) {
  // 16B per lane, wave-uniform LDS base; HW writes base + lane*16.
  __builtin_amdgcn_global_load_lds((glb_u32*)g, (lds_u32*)l, 16, 0, 0);
}

__device__ __forceinline__ unsigned short f2bf(float f) {
  union { __hip_bfloat16 h; unsigned short u; } c;
  c.h = __float2bfloat16(f);        // compiler emits v_cvt_pk_bf16_f32 pairs
  return c.u;
}

__device__ __forceinline__ float bf2f(unsigned short u) {
  union { unsigned int u; float f; } c;
  c.u = ((unsigned int)u) << 16;
  return c.f;
}

__device__ __forceinline__ float gelu_exact(float v) {
  return 0.5f * v * (1.0f + erff(v * 0.7071067811865475f));
}

// ---------------------------------------------------------------------------
// Weight transpose + fp32->bf16 convert:  in (K x N) fp32  ->  out (N x K) bf16
// ---------------------------------------------------------------------------
__global__ __launch_bounds__(256) void transpose_convert(
    const float* __restrict__ in, unsigned short* __restrict__ outp, int K, int N) {
  __shared__ float tile[32][33];
  const int bk = blockIdx.x * 32, bn = blockIdx.y * 32;
  const int t = threadIdx.x;
  const int r = t >> 5, c = t & 31;
#pragma unroll
  for (int p = 0; p < 4; ++p)
    tile[r + p * 8][c] = in[(size_t)(bk + r + p * 8) * N + bn + c];
  __syncthreads();
#pragma unroll
  for (int p = 0; p < 4; ++p)
    outp[(size_t)(bn + r + p * 8) * K + bk + c] = f2bf(tile[c][r + p * 8]);
}

// ---------------------------------------------------------------------------
// V transpose: qkv V-part (b,q,h,d) -> vT[bh][d][q]  (bf16, per-(b,h) 64x2048)
// ---------------------------------------------------------------------------
__global__ __launch_bounds__(256) void transpose_v(
    const unsigned short* __restrict__ qkv, unsigned short* __restrict__ vT) {
  __shared__ unsigned short tile[64][68];   // pad to de-pattern banks
  const int bh = blockIdx.y;                // 0..63
  const int b = bh >> 4, h = bh & 15;
  const int q0 = blockIdx.x * 64;
  const int t = threadIdx.x;
  const int r = t >> 3, c8 = t & 7;         // r: 0..31
#pragma unroll
  for (int p = 0; p < 2; ++p) {
    const int q = r + p * 32;
    short8 v = *(const short8*)(qkv + (size_t)(b * 2048 + q0 + q) * 3072 + 2048 + h * 64 + c8 * 8);
    *(short8*)(&tile[q][c8 * 8]) = v;
  }
  __syncthreads();
#pragma unroll
  for (int p = 0; p < 2; ++p) {
    const int d = r + p * 32;
    short8 v;
#pragma unroll
    for (int j = 0; j < 8; ++j) v[j] = tile[c8 * 8 + j][d];
    *(short8*)(vT + ((size_t)bh * 64 + d) * 2048 + q0 + c8 * 8) = v;
  }
}

// ---------------------------------------------------------------------------
// LayerNorm: x (rows x 1024) fp32 -> out bf16.  One 256-thread block per row.
// ---------------------------------------------------------------------------
__global__ __launch_bounds__(256) void layernorm_k(
    const float* __restrict__ x, const float* __restrict__ gamma,
    const float* __restrict__ beta, unsigned short* __restrict__ out) {
  const int row = blockIdx.x;
  const int t = threadIdx.x;
  const float4 v = ((const float4*)(x + (size_t)row * 1024))[t];
  float s = v.x + v.y + v.z + v.w;
  float sq = v.x * v.x + v.y * v.y + v.z * v.z + v.w * v.w;
#pragma unroll
  for (int sh = 32; sh >= 1; sh >>= 1) {
    s += __shfl_xor(s, sh);
    sq += __shfl_xor(sq, sh);
  }
  __shared__ float ps[4], pq[4];
  if ((t & 63) == 0) { ps[t >> 6] = s; pq[t >> 6] = sq; }
  __syncthreads();
  s = ps[0] + ps[1] + ps[2] + ps[3];
  sq = pq[0] + pq[1] + pq[2] + pq[3];
  const float mean = s * (1.0f / 1024.0f);
  const float var = sq * (1.0f / 1024.0f) - mean * mean;
  const float rstd = rsqrtf(var + 1e-5f);
  const float4 g = ((const float4*)gamma)[t];
  const float4 be = ((const float4*)beta)[t];
  ushort4 ov;
  ov.x = f2bf(g.x * (v.x - mean) * rstd + be.x);
  ov.y = f2bf(g.y * (v.y - mean) * rstd + be.y);
  ov.z = f2bf(g.z * (v.z - mean) * rstd + be.z);
  ov.w = f2bf(g.w * (v.w - mean) * rstd + be.w);
  ((ushort4*)(out + (size_t)row * 1024))[t] = ov;
}

// ---------------------------------------------------------------------------
// GEMM  C(MxN) = A(MxK,bf16) * Bt(NxK,bf16)^T  + bias [+gelu] [+f32 residual]
// 128x128 tile, BK=64, 4 waves (2x2), per-wave 64x64 = 4x4 frags of 16x16x32.
// Staging: global_load_lds width=16, linear LDS dest, PRE-SWIZZLED global
// source (rule #21): LDS[r][c8] = global[r][c8 ^ (r&7)]; reads XOR again.
// XCD-aware block swizzle (nwg % 8 == 0 for all launches here).
// EPI: 0 = bf16 out (bias), 1 = bf16 out (bias+gelu), 2 = f32 out (bias+res)
// ---------------------------------------------------------------------------
template <int EPI>
__global__ __launch_bounds__(256) void gemm_bt(
    const unsigned short* __restrict__ A, const unsigned short* __restrict__ Bt,
    const float* __restrict__ bias, const float* __restrict__ res,
    void* __restrict__ outp, int M, int N, int K) {
  __shared__ unsigned short lA[128 * 64];
  __shared__ unsigned short lB[128 * 64];
  const int t = threadIdx.x;
  const int lane = t & 63;
  const int wave = t >> 6;
  const int l15 = lane & 15, l4 = lane >> 4;

  // XCD swizzle: consecutive dispatch ids round-robin XCDs; give each XCD a
  // contiguous chunk of the work space so L2 panels are shared within an XCD.
  const int gx = gridDim.x;
  int lin = blockIdx.y * gx + blockIdx.x;
  const int cpx = (gx * gridDim.y) >> 3;
  lin = (lin & 7) * cpx + (lin >> 3);
  const int m0 = (lin / gx) * 128, n0 = (lin % gx) * 128;
  const int wm = (wave >> 1) * 64, wn = (wave & 1) * 64;

  f32x4 acc[4][4];
#pragma unroll
  for (int a_ = 0; a_ < 4; ++a_)
#pragma unroll
    for (int b_ = 0; b_ < 4; ++b_) acc[a_][b_] = f32x4{0.f, 0.f, 0.f, 0.f};

  // staging geometry (per wave: 4 chunks of A + 4 of B; chunk = 1KB = 8 rows)
  const int s_sub = lane >> 3;               // 0..7 row-in-chunk
  const int s_c8 = lane & 7;                 // 16B column chunk

  for (int k0 = 0; k0 < K; k0 += 64) {
    __syncthreads();                         // prior iter's LDS reads done
#pragma unroll
    for (int j = 0; j < 4; ++j) {
      const int chunk = wave * 4 + j;        // 0..15
      const int r = chunk * 8 + s_sub;       // 0..127
      const int c8s = s_c8 ^ (r & 7);        // pre-swizzled source column
      gload16(A + (size_t)(m0 + r) * K + k0 + c8s * 8, lA + chunk * 512);
      gload16(Bt + (size_t)(n0 + r) * K + k0 + c8s * 8, lB + chunk * 512);
    }
    __syncthreads();                         // drains vmcnt -> LDS ready
#pragma unroll
    for (int ks = 0; ks < 2; ++ks) {
      short8 af[4], bf[4];
#pragma unroll
      for (int mf = 0; mf < 4; ++mf) {
        const int r = wm + mf * 16 + l15;
        af[mf] = *(const short8*)(lA + r * 64 + (((ks * 4 + l4) ^ (r & 7)) * 8));
      }
#pragma unroll
      for (int nf = 0; nf < 4; ++nf) {
        const int r = wn + nf * 16 + l15;
        bf[nf] = *(const short8*)(lB + r * 64 + (((ks * 4 + l4) ^ (r & 7)) * 8));
      }
#pragma unroll
      for (int mf = 0; mf < 4; ++mf)
#pragma unroll
        for (int nf = 0; nf < 4; ++nf)
          acc[mf][nf] = __builtin_amdgcn_mfma_f32_16x16x32_bf16(
              af[mf], bf[nf], acc[mf][nf], 0, 0, 0);
    }
  }
  // epilogue: D row = (lane>>4)*4 + reg, col = lane&15  (m89-verified layout)
#pragma unroll
  for (int mf = 0; mf < 4; ++mf)
#pragma unroll
    for (int i = 0; i < 4; ++i) {
      const int gm = m0 + wm + mf * 16 + l4 * 4 + i;
#pragma unroll
      for (int nf = 0; nf < 4; ++nf) {
        const int gn = n0 + wn + nf * 16 + l15;
        float v = acc[mf][nf][i] + bias[gn];
        if constexpr (EPI == 1) v = gelu_exact(v);
        if constexpr (EPI == 2) {
          v += res[(size_t)gm * N + gn];
          ((float*)outp)[(size_t)gm * N + gn] = v;
        } else {
          ((unsigned short*)outp)[(size_t)gm * N + gn] = f2bf(v);
        }
      }
    }
}

// ---------------------------------------------------------------------------
// Attention tile: one 32x64 S-tile -> online softmax -> O += P V.
// Q pre-scaled by 1/8; MASK only instantiated for diagonal tiles.
// Row-sum accumulated via MFMA with all-ones B fragment (os).
// ---------------------------------------------------------------------------
template <bool MASK>
__device__ __forceinline__ void attn_tile(
    int kt, int q0, const short8 (&qf)[2][2], f32x4 (&o)[2][4], f32x4 (&os)[2],
    float (&mrow)[2][4],
    const unsigned short* lK, const unsigned short* lV,
    unsigned short* lp, int l15, int l4) {
  // S = Q K^T  (Q pre-scaled)
  f32x4 s[2][4];
#pragma unroll
  for (int mf = 0; mf < 2; ++mf)
#pragma unroll
    for (int nf = 0; nf < 4; ++nf) s[mf][nf] = f32x4{0.f, 0.f, 0.f, 0.f};
#pragma unroll
  for (int ks = 0; ks < 2; ++ks) {
    short8 kf[4];
#pragma unroll
    for (int nf = 0; nf < 4; ++nf) {
      const int r = nf * 16 + l15;
      kf[nf] = *(const short8*)(lK + r * 64 + (((ks * 4 + l4) ^ (r & 7)) * 8));
    }
#pragma unroll
    for (int mf = 0; mf < 2; ++mf)
#pragma unroll
      for (int nf = 0; nf < 4; ++nf)
        s[mf][nf] = __builtin_amdgcn_mfma_f32_16x16x32_bf16(
            qf[mf][ks], kf[nf], s[mf][nf], 0, 0, 0);
  }
  if constexpr (MASK) {
#pragma unroll
    for (int mf = 0; mf < 2; ++mf)
#pragma unroll
      for (int i = 0; i < 4; ++i) {
        const int gq = q0 + mf * 16 + l4 * 4 + i;
#pragma unroll
        for (int nf = 0; nf < 4; ++nf) {
          const int gk = kt * 64 + nf * 16 + l15;
          s[mf][nf][i] = (gk <= gq) ? s[mf][nf][i] : -1e30f;
        }
      }
  }
  // online softmax: row max via 16-lane shuffle reduce; sum via MFMA below
  float alpha[2][4];
#pragma unroll
  for (int mf = 0; mf < 2; ++mf)
#pragma unroll
    for (int i = 0; i < 4; ++i) {
      float mx = fmaxf(fmaxf(s[mf][0][i], s[mf][1][i]),
                       fmaxf(s[mf][2][i], s[mf][3][i]));
#pragma unroll
      for (int sh = 1; sh < 16; sh <<= 1) mx = fmaxf(mx, __shfl_xor(mx, sh));
      const float mnew = fmaxf(mrow[mf][i], mx);
      alpha[mf][i] = __expf(mrow[mf][i] - mnew);
      mrow[mf][i] = mnew;
#pragma unroll
      for (int nf = 0; nf < 4; ++nf)
        s[mf][nf][i] = __expf(s[mf][nf][i] - mnew);
    }
  // rescale O and row-sum accumulator
#pragma unroll
  for (int mf = 0; mf < 2; ++mf) {
#pragma unroll
    for (int nf = 0; nf < 4; ++nf)
#pragma unroll
      for (int i = 0; i < 4; ++i) o[mf][nf][i] *= alpha[mf][i];
#pragma unroll
    for (int i = 0; i < 4; ++i) os[mf][i] *= alpha[mf][i];
  }
  // P -> bf16 -> per-wave LDS (D-layout scatter, swizzled)
#pragma unroll
  for (int mf = 0; mf < 2; ++mf)
#pragma unroll
    for (int nf = 0; nf < 4; ++nf)
#pragma unroll
      for (int i = 0; i < 4; ++i) {
        const int qr = mf * 16 + l4 * 4 + i;
        const int kb = (nf * 16 + l15) * 2;
        const int byt = qr * 128 + (kb ^ ((qr & 7) << 4));
        lp[byt >> 1] = f2bf(s[mf][nf][i]);
      }
  // O += P V ; os += P * ones
  const short8 ones = {16256, 16256, 16256, 16256, 16256, 16256, 16256, 16256};
#pragma unroll
  for (int ks = 0; ks < 2; ++ks) {
    short8 pf[2], vf[4];
#pragma unroll
    for (int mf = 0; mf < 2; ++mf) {
      const int r = mf * 16 + l15;
      pf[mf] = *(const short8*)(lp + r * 64 + (((ks * 4 + l4) ^ (r & 7)) * 8));
    }
#pragma unroll
    for (int nf = 0; nf < 4; ++nf) {
      const int r = nf * 16 + l15;   // d index
      vf[nf] = *(const short8*)(lV + r * 64 + (((ks * 4 + l4) ^ (r & 7)) * 8));
    }
#pragma unroll
    for (int mf = 0; mf < 2; ++mf) {
      os[mf] = __builtin_amdgcn_mfma_f32_16x16x32_bf16(pf[mf], ones, os[mf], 0, 0, 0);
#pragma unroll
      for (int nf = 0; nf < 4; ++nf)
        o[mf][nf] = __builtin_amdgcn_mfma_f32_16x16x32_bf16(
            pf[mf], vf[nf], o[mf][nf], 0, 0, 0);
    }
  }
}

// ---------------------------------------------------------------------------
// Causal flash attention. qkv: (8192 x 3072) bf16, vT: [bh][64][2048] bf16.
// Grid (64, 16): x = bh (=> bh%8 -> fixed XCD, K/V L2 locality),
// y: qb = 15 - y => heaviest blocks dispatched first (LPT backfill).
// Block = one q-tile (128 rows), 4 waves x 32 rows. K/V staged per 64-k tile.
// launch_bounds (256,2): 256-VGPR budget -> no spill (r4 post-mortem).
// ---------------------------------------------------------------------------
__global__ __launch_bounds__(256, 2) void attn_kernel(
    const unsigned short* __restrict__ qkv, const unsigned short* __restrict__ vT,
    unsigned short* __restrict__ attno) {
  __shared__ unsigned short lK[64 * 64];      // [krow][d]  swizzled
  __shared__ unsigned short lV[64 * 64];      // [d][krow]  swizzled
  __shared__ unsigned short lP[4][32 * 64];   // per-wave P, swizzled

  const int bh = blockIdx.x;                  // 0..63
  const int qb = 15 - blockIdx.y;             // heavy first
  const int b = bh >> 4, h = bh & 15;
  const int t = threadIdx.x;
  const int wave = t >> 6, lane = t & 63;
  const int l15 = lane & 15, l4 = lane >> 4;

  const unsigned short* qkvb = qkv + (size_t)b * 2048 * 3072;
  const unsigned short* vTb = vT + (size_t)bh * 64 * 2048;
  const int q0 = qb * 128 + wave * 32;

  // Q fragments hoisted + folded 1/8 scale (exact in bf16: x * 2^-3)
  short8 qf[2][2];
#pragma unroll
  for (int mf = 0; mf < 2; ++mf)
#pragma unroll
    for (int ks = 0; ks < 2; ++ks) {
      const int qr = q0 + mf * 16 + l15;
      const int d = ks * 32 + l4 * 8;
      short8 raw = *(const short8*)(qkvb + (size_t)qr * 3072 + h * 64 + d);
#pragma unroll
      for (int j = 0; j < 8; ++j)
        qf[mf][ks][j] = (short)f2bf(bf2f((unsigned short)raw[j]) * 0.125f);
    }

  f32x4 o[2][4], os[2];
  float mrow[2][4];
#pragma unroll
  for (int mf = 0; mf < 2; ++mf) {
    os[mf] = f32x4{0.f, 0.f, 0.f, 0.f};
#pragma unroll
    for (int i = 0; i < 4; ++i) mrow[mf][i] = -1e30f;
#pragma unroll
    for (int nf = 0; nf < 4; ++nf) o[mf][nf] = f32x4{0.f, 0.f, 0.f, 0.f};
  }

  const int s_sub = lane >> 3, s_c8 = lane & 7;
  const int ktiles = qb * 2 + 2;
  for (int kt = 0; kt < ktiles; ++kt) {
    __syncthreads();                           // prior tile reads done
    // stage K [k][d] and V^T [d][k] via global_load_lds (2 chunks each/wave)
#pragma unroll
    for (int j = 0; j < 2; ++j) {
      const int chunk = wave * 2 + j;          // 0..7
      const int r = chunk * 8 + s_sub;         // 0..63
      const int c8s = s_c8 ^ (r & 7);
      gload16(qkvb + (size_t)(kt * 64 + r) * 3072 + 1024 + h * 64 + c8s * 8,
              lK + chunk * 512);
      gload16(vTb + (size_t)r * 2048 + kt * 64 + c8s * 8, lV + chunk * 512);
    }
    __syncthreads();

    if ((kt * 64) <= (q0 + 31)) {
      if ((kt * 64 + 63) <= q0)
        attn_tile<false>(kt, q0, qf, o, os, mrow, lK, lV, lP[wave], l15, l4);
      else
        attn_tile<true>(kt, q0, qf, o, os, mrow, lK, lV, lP[wave], l15, l4);
    }
  }

  // epilogue: O /= rowsum, store bf16 at (b*2048+q, h*64+d)
#pragma unroll
  for (int mf = 0; mf < 2; ++mf)
#pragma unroll
    for (int i = 0; i < 4; ++i) {
      const float inv = 1.0f / os[mf][i];
      const int gq = q0 + mf * 16 + l4 * 4 + i;
#pragma unroll
      for (int nf = 0; nf < 4; ++nf) {
        const int gd = nf * 16 + l15;
        attno[(size_t)(b * 2048 + gq) * 1024 + h * 64 + gd] =
            f2bf(o[mf][nf][i] * inv);
      }
    }
}

// ---------------------------------------------------------------------------
extern "C" void kernel_launch(void* const* d_in, const int* in_sizes, int n_in,
                              void* d_out, int out_size, void* d_ws, size_t ws_size,
                              hipStream_t stream) {
  const float* x    = (const float*)d_in[0];
  const float* g1   = (const float*)d_in[1];
  const float* be1  = (const float*)d_in[2];
  const float* Wqkv = (const float*)d_in[3];
  const float* bqkv = (const float*)d_in[4];
  const float* Wo   = (const float*)d_in[5];
  const float* bo   = (const float*)d_in[6];
  const float* g2   = (const float*)d_in[7];
  const float* be2  = (const float*)d_in[8];
  const float* W1   = (const float*)d_in[9];
  const float* b1   = (const float*)d_in[10];
  const float* W2   = (const float*)d_in[11];
  const float* b2   = (const float*)d_in[12];
  float* out = (float*)d_out;
  char* ws = (char*)d_ws;

  const size_t MB = 1024ull * 1024ull;
  // lifetimes: qkv (0..64MB) dies before gelu-out reuses it; ln1 (64..80MB)
  // dies before attn-out reuses it; vT (80..96MB) dies before x2 (80..112MB)
  // is written (step 5).
  unsigned short* qkv_g    = (unsigned short*)(ws + 0);        // 48MB qkv / 64MB gelu
  unsigned short* ln1_attn = (unsigned short*)(ws + 64 * MB);  // 16MB ln1 / attn-out
  float*          x2       = (float*)(ws + 80 * MB);           // 32MB
  unsigned short* vT       = (unsigned short*)(ws + 80 * MB);  // 16MB (dead by step 5)
  unsigned short* hbuf     = (unsigned short*)(ws + 112 * MB); // 16MB
  unsigned short* wqkv_bt  = (unsigned short*)(ws + 128 * MB); // 6MB  (3072x1024)
  unsigned short* wo_bt    = (unsigned short*)(ws + 134 * MB); // 2MB  (1024x1024)
  unsigned short* w1_bt    = (unsigned short*)(ws + 136 * MB); // 8MB  (4096x1024)
  unsigned short* w2_bt    = (unsigned short*)(ws + 144 * MB); // 8MB  (1024x4096)

  // 1) weight transposes (fp32 -> bf16, N x K layout)
  transpose_convert<<<dim3(1024 / 32, 3072 / 32), 256, 0, stream>>>(Wqkv, wqkv_bt, 1024, 3072);
  transpose_convert<<<dim3(1024 / 32, 1024 / 32), 256, 0, stream>>>(Wo, wo_bt, 1024, 1024);
  transpose_convert<<<dim3(1024 / 32, 4096 / 32), 256, 0, stream>>>(W1, w1_bt, 1024, 4096);
  transpose_convert<<<dim3(4096 / 32, 1024 / 32), 256, 0, stream>>>(W2, w2_bt, 4096, 1024);

  // 2) ln1(x) -> bf16
  layernorm_k<<<8192, 256, 0, stream>>>(x, g1, be1, ln1_attn);

  // 3) qkv = ln1 @ Wqkv + b_qkv   (8192 x 3072)
  gemm_bt<0><<<dim3(3072 / 128, 8192 / 128), 256, 0, stream>>>(
      ln1_attn, wqkv_bt, bqkv, nullptr, qkv_g, 8192, 3072, 1024);

  // 3b) V -> vT[bh][d][q]
  transpose_v<<<dim3(2048 / 64, 64), 256, 0, stream>>>(qkv_g, vT);

  // 4) causal attention -> ln1_attn (reused as attn-out, 8192 x 1024 bf16)
  attn_kernel<<<dim3(64, 16), 256, 0, stream>>>(qkv_g, vT, ln1_attn);

  // 5) x2 = x + attn @ Wo + b_o  (fp32)
  gemm_bt<2><<<dim3(1024 / 128, 8192 / 128), 256, 0, stream>>>(
      ln1_attn, wo_bt, bo, x, x2, 8192, 1024, 1024);

  // 6) ln2(x2) -> bf16
  layernorm_k<<<8192, 256, 0, stream>>>(x2, g2, be2, hbuf);

  // 7) g = gelu(h @ W1 + b1)  (8192 x 4096 bf16), reuses qkv region
  gemm_bt<1><<<dim3(4096 / 128, 8192 / 128), 256, 0, stream>>>(
      hbuf, w1_bt, b1, nullptr, qkv_g, 8192, 4096, 1024);

  // 8) out = x2 + g @ W2 + b2  (fp32)
  gemm_bt<2><<<dim3(1024 / 128, 8192 / 128), 256, 0, stream>>>(
      qkv_g, w2_bt, b2, x2, out, 8192, 1024, 4096);
}